// Round 2
// baseline (3377.332 us; speedup 1.0000x reference)
//
#include <hip/hip_runtime.h>
#include <stdint.h>

typedef _Float16 f16;
typedef __attribute__((ext_vector_type(8))) _Float16 f16x8;
typedef __attribute__((ext_vector_type(4))) _Float16 f16x4;
typedef __attribute__((ext_vector_type(4))) float f32x4;

#define NB 8192
#define KD 4096
#define NL 5
#define NT 16777216ULL   // 4096*4096 elements per big score tensor
#define JBIG 8388608u    // n/2
#define L2CAP 2048

__device__ __forceinline__ unsigned absbits(float x) {
  return __float_as_uint(x) & 0x7fffffffu;
}

// ---------------- cast x -> fp16 ----------------
__global__ __launch_bounds__(256) void k_cast(const float* __restrict__ x, f16* __restrict__ h, int n4) {
  int i = blockIdx.x * 256 + threadIdx.x;
  int stride = gridDim.x * 256;
  for (; i < n4; i += stride) {
    f32x4 v = ((const f32x4*)x)[i];
    f16x4 o;
    o.x = (f16)v.x; o.y = (f16)v.y; o.z = (f16)v.z; o.w = (f16)v.w;
    ((f16x4*)h)[i] = o;
  }
}

// ---------------- pass A: 12-bit histogram of abs bits ----------------
// 2 LDS copies (65.6KB for 4 copies exceeded the 64KB static limit).
__global__ __launch_bounds__(256) void k_passA(const float* __restrict__ s1, const float* __restrict__ s2,
                                               unsigned* __restrict__ histA) {
  __shared__ unsigned h[2][4100];  // 2 copies, +4 pad; 32,800 B
  int t = blockIdx.x >> 6;
  int blk = blockIdx.x & 63;
  const float* base = (t < 5) ? (s1 + (size_t)t * NT) : (s2 + (size_t)(t - 5) * NT);
  for (int i = threadIdx.x; i < 2 * 4100; i += 256) ((unsigned*)h)[i] = 0;
  __syncthreads();
  const f32x4* p = (const f32x4*)base + (size_t)blk * 65536;
  unsigned* hc = h[threadIdx.x & 1];
  for (int i = threadIdx.x; i < 65536; i += 256) {
    f32x4 v = p[i];
    atomicAdd(&hc[absbits(v.x) >> 19], 1u);
    atomicAdd(&hc[absbits(v.y) >> 19], 1u);
    atomicAdd(&hc[absbits(v.z) >> 19], 1u);
    atomicAdd(&hc[absbits(v.w) >> 19], 1u);
  }
  __syncthreads();
  unsigned* g = histA + t * 4096;
  for (int i = threadIdx.x; i < 4096; i += 256) {
    unsigned s = h[0][i] + h[1][i];
    if (s) atomicAdd(&g[i], s);
  }
}

// ---------------- generic histogram reduce: find bin containing rank j ----------------
__global__ __launch_bounds__(256) void k_reduce(const unsigned* __restrict__ hist, const unsigned* __restrict__ jin,
                                                unsigned* __restrict__ bino, unsigned* __restrict__ jout) {
  int t = blockIdx.x;
  __shared__ unsigned sh[4096];
  __shared__ unsigned part[256];
  const unsigned* g = hist + t * 4096;
  unsigned ps = 0;
  for (int i = 0; i < 16; i++) {
    unsigned v = g[threadIdx.x * 16 + i];
    sh[threadIdx.x * 16 + i] = v;
    ps += v;
  }
  part[threadIdx.x] = ps;
  __syncthreads();
  if (threadIdx.x == 0) {
    unsigned j = jin ? jin[t] : JBIG;
    unsigned cum = 0;
    int b = 4095;
    int seg = 0;
    for (; seg < 256; seg++) {
      if (cum + part[seg] > j) break;
      cum += part[seg];
    }
    if (seg < 256) {
      for (int q = 0; q < 16; q++) {
        int bb = seg * 16 + q;
        if (cum + sh[bb] > j) { b = bb; break; }
        cum += sh[bb];
      }
    }
    bino[t] = (unsigned)b;
    jout[t] = j - cum;
  }
}

// ---------------- pass B: refine next 12 bits within pass-A bin ----------------
__global__ __launch_bounds__(256) void k_passB(const float* __restrict__ s1, const float* __restrict__ s2,
                                               const unsigned* __restrict__ binA, unsigned* __restrict__ histB) {
  __shared__ unsigned h[4096];
  int t = blockIdx.x >> 6, blk = blockIdx.x & 63;
  unsigned bA = binA[t];
  const float* base = (t < 5) ? (s1 + (size_t)t * NT) : (s2 + (size_t)(t - 5) * NT);
  for (int i = threadIdx.x; i < 4096; i += 256) h[i] = 0;
  __syncthreads();
  const f32x4* p = (const f32x4*)base + (size_t)blk * 65536;
  for (int i = threadIdx.x; i < 65536; i += 256) {
    f32x4 v = p[i];
    unsigned u;
    u = absbits(v.x); if ((u >> 19) == bA) atomicAdd(&h[(u >> 7) & 4095], 1u);
    u = absbits(v.y); if ((u >> 19) == bA) atomicAdd(&h[(u >> 7) & 4095], 1u);
    u = absbits(v.z); if ((u >> 19) == bA) atomicAdd(&h[(u >> 7) & 4095], 1u);
    u = absbits(v.w); if ((u >> 19) == bA) atomicAdd(&h[(u >> 7) & 4095], 1u);
  }
  __syncthreads();
  unsigned* g = histB + t * 4096;
  for (int i = threadIdx.x; i < 4096; i += 256) if (h[i]) atomicAdd(&g[i], h[i]);
}

// ---------------- pass C: collect (bits,idx) of elements in the 24-bit bin ----------------
__global__ __launch_bounds__(256) void k_passC(const float* __restrict__ s1, const float* __restrict__ s2,
                                               const unsigned* __restrict__ binA, const unsigned* __restrict__ binB,
                                               unsigned* __restrict__ n2, unsigned long long* __restrict__ list2) {
  int t = blockIdx.x >> 6, blk = blockIdx.x & 63;
  unsigned pref = (binA[t] << 12) | binB[t];
  const float* base = (t < 5) ? (s1 + (size_t)t * NT) : (s2 + (size_t)(t - 5) * NT);
  const f32x4* p = (const f32x4*)base + (size_t)blk * 65536;
  unsigned ibase = (unsigned)blk * 262144u;
  for (int i = threadIdx.x; i < 65536; i += 256) {
    f32x4 v = p[i];
    unsigned idx0 = ibase + (unsigned)i * 4u;
#define CHK(c, comp) { unsigned u = absbits(comp); if ((u >> 7) == pref) { \
      unsigned pos = atomicAdd(&n2[t], 1u); \
      if (pos < L2CAP) list2[(size_t)t * L2CAP + pos] = ((unsigned long long)u << 32) | (idx0 + c); } }
    CHK(0u, v.x) CHK(1u, v.y) CHK(2u, v.z) CHK(3u, v.w)
#undef CHK
  }
}

// ---------------- reduce C: exact threshold + stable-tie exceptions ----------------
__global__ __launch_bounds__(256) void k_reduceC(const unsigned* __restrict__ n2, const unsigned long long* __restrict__ list2,
                                                 const unsigned* __restrict__ jB, unsigned* __restrict__ T,
                                                 unsigned* __restrict__ nexc, unsigned* __restrict__ exc) {
  int t = blockIdx.x;
  __shared__ unsigned long long key[L2CAP];
  __shared__ unsigned rnk[L2CAP];
  __shared__ unsigned sT;
  if (threadIdx.x == 0) sT = 0xffffffffu;
  unsigned n = n2[t]; if (n > L2CAP) n = L2CAP;
  for (int i = threadIdx.x; i < (int)n; i += 256) key[i] = list2[(size_t)t * L2CAP + i];
  __syncthreads();
  unsigned jj = jB[t];
  for (int e = threadIdx.x; e < (int)n; e += 256) {
    unsigned long long ke = key[e];
    unsigned r = 0;
    for (unsigned f = 0; f < n; f++) r += (key[f] < ke) ? 1u : 0u;
    rnk[e] = r;
    if (r == jj) sT = (unsigned)(ke >> 32);
  }
  __syncthreads();
  if (threadIdx.x == 0) T[t] = sT;
  unsigned sTl = sT;
  for (int e = threadIdx.x; e < (int)n; e += 256) {
    if ((unsigned)(key[e] >> 32) == sTl && rnk[e] < jj) {
      unsigned pos = atomicAdd(&nexc[t], 1u);
      if (pos < L2CAP) exc[(size_t)t * L2CAP + pos] = (unsigned)(key[e] & 0xffffffffu);
    }
  }
}

// ---------------- weight generation: W = (|s1|>=T1) - (|s2|>=T2) as fp16 ----------------
__global__ __launch_bounds__(256) void k_wgen(const float* __restrict__ s1, const float* __restrict__ s2,
                                              const unsigned* __restrict__ T, f16* __restrict__ W) {
  size_t i = (size_t)blockIdx.x * 256 + threadIdx.x;
  size_t stride = (size_t)gridDim.x * 256;
  const size_t total = (size_t)NL * NT / 4;
  for (; i < total; i += stride) {
    unsigned l = (unsigned)(i >> 22);  // NT/4 = 2^22
    unsigned T1 = T[l], T2 = T[5 + l];
    f32x4 a = ((const f32x4*)s1)[i];
    f32x4 b = ((const f32x4*)s2)[i];
    f16x4 w;
    w.x = (f16)(float)((int)(absbits(a.x) >= T1) - (int)(absbits(b.x) >= T2));
    w.y = (f16)(float)((int)(absbits(a.y) >= T1) - (int)(absbits(b.y) >= T2));
    w.z = (f16)(float)((int)(absbits(a.z) >= T1) - (int)(absbits(b.z) >= T2));
    w.w = (f16)(float)((int)(absbits(a.w) >= T1) - (int)(absbits(b.w) >= T2));
    ((f16x4*)W)[i] = w;
  }
}

// ---------------- tie fixup (few elements; recompute exactly) ----------------
__global__ __launch_bounds__(256) void k_fixup(const float* __restrict__ s1, const float* __restrict__ s2,
                                               const unsigned* __restrict__ T, const unsigned* __restrict__ nexc,
                                               const unsigned* __restrict__ exc, f16* __restrict__ W) {
  int t = blockIdx.x;           // 0..9
  int l = t % 5;
  int side = t / 5;             // 0: scores1, 1: scores2
  int other = side ? t - 5 : t + 5;
  unsigned ne = nexc[t]; if (ne > L2CAP) ne = L2CAP;
  unsigned no = nexc[other]; if (no > L2CAP) no = L2CAP;
  for (unsigned e = threadIdx.x; e < ne; e += 256) {
    unsigned f = exc[(size_t)t * L2CAP + e];
    size_t g = (size_t)l * NT + f;
    int m1 = (absbits(s1[g]) >= T[l]) ? 1 : 0;
    int m2 = (absbits(s2[g]) >= T[5 + l]) ? 1 : 0;
    if (side == 0) m1 = 0; else m2 = 0;
    for (unsigned q = 0; q < no; q++)
      if (exc[(size_t)other * L2CAP + q] == f) { if (side == 0) m2 = 0; else m1 = 0; }
    W[g] = (f16)(float)(m1 - m2);
  }
}

// ---------------- small output-layer masks: exact stable rank over 8192 ----------------
__global__ __launch_bounds__(256) void k_small(const float* __restrict__ s1o, const float* __restrict__ s2o,
                                               float* __restrict__ mo) {
  __shared__ unsigned su[8192];
  int t = blockIdx.x >> 5, seg = blockIdx.x & 31;
  const float* s = t ? s2o : s1o;
  for (int i = threadIdx.x; i < 8192; i += 256) su[i] = absbits(s[i]);
  __syncthreads();
  int e = seg * 256 + threadIdx.x;
  unsigned ue = su[e];
  unsigned r = 0;
  for (int k = 0; k < 8192; k++) {
    unsigned uk = su[k];
    r += (uk < ue || (uk == ue && k < e)) ? 1u : 0u;
  }
  mo[t * 8192 + e] = (r >= 4096u) ? 1.0f : 0.0f;
}

// ---------------- GEMM: O = relu(A @ W^T + 2b scaled)/32 in fp16 (m97 structure) ----------------
__device__ __forceinline__ void gload16(const void* g, void* s) {
  __builtin_amdgcn_global_load_lds((const __attribute__((address_space(1))) unsigned*)g,
                                   (__attribute__((address_space(3))) unsigned*)s, 16, 0, 0);
}

__global__ __launch_bounds__(256, 2) void k_gemm(const f16* __restrict__ A, const f16* __restrict__ W,
                                                 const float* __restrict__ bias, float bscale,
                                                 f16* __restrict__ O) {
  __shared__ f16 As[2][128 * 32];
  __shared__ f16 Bs[2][128 * 32];
  const int tid = threadIdx.x;
  const int wave = tid >> 6, lane = tid & 63;
  unsigned bid = blockIdx.x;
  bid = (bid & 7) * 256 + (bid >> 3);  // XCD swizzle, 2048 % 8 == 0 -> bijective
  const int m0 = (int)(bid & 63) * 128;
  const int n0 = (int)(bid >> 6) * 128;
  const int wr = wave >> 1, wc = wave & 1;
  const int c0 = tid, c1 = tid + 256;
  const f16* ga0 = A + (size_t)(m0 + (c0 >> 2)) * KD + (c0 & 3) * 8;
  const f16* ga1 = A + (size_t)(m0 + (c1 >> 2)) * KD + (c1 & 3) * 8;
  const f16* gb0 = W + (size_t)(n0 + (c0 >> 2)) * KD + (c0 & 3) * 8;
  const f16* gb1 = W + (size_t)(n0 + (c1 >> 2)) * KD + (c1 & 3) * 8;

  f32x4 acc[4][4] = {};

  {
    char* dA = (char*)&As[0][0] + wave * 1024;
    char* dB = (char*)&Bs[0][0] + wave * 1024;
    gload16(ga0, dA); gload16(ga1, dA + 4096);
    gload16(gb0, dB); gload16(gb1, dB + 4096);
  }
  __syncthreads();
  int cur = 0;
  const int rr = lane & 15;
  const int kg = (lane >> 4) * 8;
  for (int kt = 0; kt < 128; kt++) {
    if (kt + 1 < 128) {
      int ko = (kt + 1) * 32;
      char* dA = (char*)&As[cur ^ 1][0] + wave * 1024;
      char* dB = (char*)&Bs[cur ^ 1][0] + wave * 1024;
      gload16(ga0 + ko, dA); gload16(ga1 + ko, dA + 4096);
      gload16(gb0 + ko, dB); gload16(gb1 + ko, dB + 4096);
    }
    const f16* as = &As[cur][0];
    const f16* bs = &Bs[cur][0];
    f16x8 af[4], bf[4];
#pragma unroll
    for (int i = 0; i < 4; i++) af[i] = *(const f16x8*)(as + (wr * 64 + i * 16 + rr) * 32 + kg);
#pragma unroll
    for (int j = 0; j < 4; j++) bf[j] = *(const f16x8*)(bs + (wc * 64 + j * 16 + rr) * 32 + kg);
#pragma unroll
    for (int i = 0; i < 4; i++)
#pragma unroll
      for (int j = 0; j < 4; j++)
        acc[i][j] = __builtin_amdgcn_mfma_f32_16x16x32_f16(af[i], bf[j], acc[i][j], 0, 0, 0);
    __syncthreads();
    cur ^= 1;
  }
  const int row4 = (lane >> 4) * 4;
  const int cc = lane & 15;
#pragma unroll
  for (int i = 0; i < 4; i++) {
    const int m = m0 + wr * 64 + i * 16 + row4;
#pragma unroll
    for (int j = 0; j < 4; j++) {
      const int n = n0 + wc * 64 + j * 16 + cc;
      const float bb = bscale * bias[n];
      f32x4 v = acc[i][j];
#pragma unroll
      for (int r = 0; r < 4; r++) {
        float pre = v[r] + bb;
        float o = pre > 0.0f ? pre * 0.03125f : 0.0f;
        O[(size_t)(m + r) * KD + n] = (f16)o;
      }
    }
  }
}

// ---------------- output head: 4096 -> 2 -> 1 ----------------
__global__ __launch_bounds__(256) void k_out(const f16* __restrict__ H, const float* __restrict__ mo,
                                             const float* __restrict__ bo, const float* __restrict__ wl,
                                             float* __restrict__ out) {
  int b = blockIdx.x;
  const f16* hr = H + (size_t)b * KD;
  int k0 = threadIdx.x * 16;
  float a0 = 0.f, a1 = 0.f;
#pragma unroll
  for (int q = 0; q < 16; q++) {
    int k = k0 + q;
    float h = (float)hr[k];
    a0 += h * (mo[k] - mo[8192 + k]);
    a1 += h * (mo[4096 + k] - mo[12288 + k]);
  }
  for (int off = 32; off > 0; off >>= 1) { a0 += __shfl_down(a0, off); a1 += __shfl_down(a1, off); }
  __shared__ float r0[4], r1[4];
  int wv = threadIdx.x >> 6;
  if ((threadIdx.x & 63) == 0) { r0[wv] = a0; r1[wv] = a1; }
  __syncthreads();
  if (threadIdx.x == 0) {
    float s0 = r0[0] + r0[1] + r0[2] + r0[3];
    float s1 = r1[0] + r1[1] + r1[2] + r1[3];
    float p0 = 33554432.0f * s0 + 2.0f * bo[0];  // 32^5
    float p1 = 33554432.0f * s1 + 2.0f * bo[1];
    p0 = p0 > 0.f ? p0 : 0.f;
    p1 = p1 > 0.f ? p1 : 0.f;
    out[b] = p0 * wl[0] + p1 * wl[1];
  }
}

extern "C" void kernel_launch(void* const* d_in, const int* in_sizes, int n_in,
                              void* d_out, int out_size, void* d_ws, size_t ws_size,
                              hipStream_t stream) {
  (void)in_sizes; (void)n_in; (void)out_size; (void)ws_size;
  const float* x   = (const float*)d_in[0];
  const float* s1h = (const float*)d_in[1];
  const float* s2h = (const float*)d_in[2];
  const float* bh  = (const float*)d_in[3];
  const float* s1o = (const float*)d_in[4];
  const float* s2o = (const float*)d_in[5];
  const float* bo  = (const float*)d_in[6];
  const float* wl  = (const float*)d_in[7];
  float* out = (float*)d_out;
  char* ws = (char*)d_ws;

  const size_t OFF_W = 0;                                  // 5*NT*2   = 167,772,160
  const size_t OFF_H0 = OFF_W + (size_t)NL * NT * 2;       // 67,108,864
  const size_t OFF_H1 = OFF_H0 + (size_t)NB * KD * 2;
  const size_t OFF_CTRL = OFF_H1 + (size_t)NB * KD * 2;    // ~302 MB total + ctrl

  f16* Wb = (f16*)(ws + OFF_W);
  f16* H0 = (f16*)(ws + OFF_H0);
  f16* H1 = (f16*)(ws + OFF_H1);
  char* ctrl = ws + OFF_CTRL;
  unsigned* histA = (unsigned*)(ctrl);
  unsigned* histB = (unsigned*)(ctrl + 163840);
  unsigned* binA = (unsigned*)(ctrl + 327680);
  unsigned* jA   = binA + 10;
  unsigned* binB = binA + 20;
  unsigned* jB   = binA + 30;
  unsigned* Tt   = binA + 40;
  unsigned* n2   = binA + 50;
  unsigned* nexc = binA + 60;
  unsigned long long* list2 = (unsigned long long*)(ctrl + 328192);
  unsigned* exc = (unsigned*)(ctrl + 328192 + 163840);
  float* mo = (float*)(ctrl + 328192 + 163840 + 81920);

  hipMemsetAsync(ctrl, 0, 328192, stream);
  k_cast<<<4096, 256, 0, stream>>>(x, H0, NB * KD / 4);
  k_small<<<64, 256, 0, stream>>>(s1o, s2o, mo);
  k_passA<<<640, 256, 0, stream>>>(s1h, s2h, histA);
  k_reduce<<<10, 256, 0, stream>>>(histA, nullptr, binA, jA);
  k_passB<<<640, 256, 0, stream>>>(s1h, s2h, binA, histB);
  k_reduce<<<10, 256, 0, stream>>>(histB, jA, binB, jB);
  k_passC<<<640, 256, 0, stream>>>(s1h, s2h, binA, binB, n2, list2);
  k_reduceC<<<10, 256, 0, stream>>>(n2, list2, jB, Tt, nexc, exc);
  k_wgen<<<8192, 256, 0, stream>>>(s1h, s2h, Tt, Wb);
  k_fixup<<<10, 256, 0, stream>>>(s1h, s2h, Tt, nexc, exc, Wb);

  const float bsc[5] = {2.0f, 2.0f / 32.0f, 2.0f / 1024.0f, 2.0f / 32768.0f, 2.0f / 1048576.0f};
  for (int l = 0; l < 5; l++) {
    const f16* Ain = (l & 1) ? H1 : H0;
    f16* Ot = (l & 1) ? H0 : H1;
    k_gemm<<<2048, 256, 0, stream>>>(Ain, Wb + (size_t)l * NT, bh + l * 4096, bsc[l], Ot);
  }
  k_out<<<8192, 256, 0, stream>>>(H1, mo, bo, wl, out);
}